// Round 12
// baseline (36.663 us; speedup 1.0000x reference)
//
#include <hip/hip_runtime.h>
#include <hip/hip_bf16.h>
#include <math.h>

// Problem constants (from reference setup_inputs)
#define B_ROWS 256
#define D_IN   128
#define D_OUT  256
#define M_LEN  4096
#define BETA   50.0f

// out layout (f32): loss[256] | mem_out[4096*256] | md_out[4096*128]
#define OFF_MEM  (B_ROWS)
#define OFF_MD   (B_ROWS + M_LEN * D_OUT)

// ---------------------------------------------------------------------------
// K1 (k_prep): enc = tanh(norm(x)@W1+b1) and loss init to +inf.  [r5-proven]
// ---------------------------------------------------------------------------
__global__ __launch_bounds__(256) void k_prep(
    const float* __restrict__ x, const float* __restrict__ mean,
    const float* __restrict__ stdv, const float* __restrict__ W1,
    const float* __restrict__ b1, float* __restrict__ enc,
    float* __restrict__ out) {
  __shared__ float sx[D_IN];
  const int b = blockIdx.x, j = threadIdx.x;
  if (j < D_IN) {
    float s = stdv[j];
    sx[j] = (s == 0.0f) ? 0.0f : (x[b * D_IN + j] - mean[j]) / s;
  }
  __syncthreads();
  float acc = b1[j];
#pragma unroll 8
  for (int k = 0; k < D_IN; ++k) acc = fmaf(sx[k], W1[k * D_OUT + j], acc);
  enc[b * D_OUT + j] = tanhf(acc);
  if (b == 0) ((unsigned int*)out)[j] = 0x7F800000u;  // +inf loss init
}

// ---------------------------------------------------------------------------
// K2 (k_dist): loss[b] = min_m sum_d |enc[b,d] - memory[m,d]|
// 256 blocks (64 m-tiles x 4 b-tiles) x 256 threads = 1 block/CU.
// Tile 64b x 64m; 4-wave k-split (wave w: k in [64w,64w+64), 2 chunks of 32).
// 8x8 microtile/lane (lane = 8 tr x 8 tc): per kk, 4 broadcast ds_read_b128
// feed 128 VALU instrs -> single wave saturates its SIMD's VALU pipe.
// LDS [kk][row^((kk>>2)<<3)]: staging b32 stores exactly 2-way; compute
// reads are 2x contiguous b128 per operand, 8-distinct + broadcast (free).
// Register discipline (r8/r9 lesson): 256-thr block (VGPR cap 256), live
// peak ~205 = acc64 + group-reads64 + next-chunk64 + addr; copy loads are
// issued only after the in-flight chunk retires. Rolled g-loop (L1I).
// Fused FULL output copy; own-region dump + 1 barrier + summer + atomicMin.
// ---------------------------------------------------------------------------
__global__ __launch_bounds__(256) void k_dist(
    const float* __restrict__ enc, const float* __restrict__ mem,
    const float4* __restrict__ mem4, const float4* __restrict__ md4,
    float* __restrict__ out) {
  __shared__ __align__(16) float sf[16384];  // 64KB: wave w owns [w*4096,+4096)

  const int t  = threadIdx.x;   // 0..255
  const int w  = t >> 6;        // wave -> k-range [64w, 64w+64)
  const int l  = t & 63;
  const int lr = l >> 3;        // staging row-base / compute tr
  const int lk = l & 7;         // staging f4-k / compute tc
  const int m0 = blockIdx.x * 64;
  const int b0 = blockIdx.y * 64;
  const int bid = blockIdx.y * 64 + blockIdx.x;  // gridDim.x == 64

  const int eb = w * 4096;         // E chunk region: [32kk][64row'] words
  const int mb = w * 4096 + 2048;  // M chunk region

  float acc[8][8] = {};
  float4 gE[8], gM[8];

  const float* ep = enc + (b0 + lr) * D_OUT + 64 * w + lk * 4;
  const float* mp = mem + (m0 + lr) * D_OUT + 64 * w + lk * 4;

  // load chunk c: rows lr+8i, f4-k = lk (+32c)  -- 8-lane 128B runs
#define LOADC(c_)                                                       \
  do {                                                                  \
    _Pragma("unroll")                                                   \
    for (int i = 0; i < 8; ++i) {                                       \
      gE[i] = *(const float4*)(ep + 32 * (c_) + i * 8 * D_OUT);         \
      gM[i] = *(const float4*)(mp + 32 * (c_) + i * 8 * D_OUT);         \
    }                                                                   \
  } while (0)

  // store to LDS: word = kk*64 + ((row) ^ ((kk>>2)<<3)), kk = 4*lk+d
#define STOREC()                                                        \
  do {                                                                  \
    _Pragma("unroll")                                                   \
    for (int i = 0; i < 8; ++i) {                                       \
      const int rw = (lr + 8 * i) ^ (lk << 3);                          \
      const int be = eb + lk * 256 + rw;                                \
      sf[be] = gE[i].x;       sf[be + 64] = gE[i].y;                    \
      sf[be + 128] = gE[i].z; sf[be + 192] = gE[i].w;                   \
      const int bm = mb + lk * 256 + rw;                                \
      sf[bm] = gM[i].x;       sf[bm + 64] = gM[i].y;                    \
      sf[bm + 128] = gM[i].z; sf[bm + 192] = gM[i].w;                   \
    }                                                                   \
  } while (0)

  // compute one staged chunk: rolled over 8 groups of 4 kk (code ~4KB)
#define COMPUTEC()                                                      \
  do {                                                                  \
    for (int g = 0; g < 8; ++g) {                                       \
      const int es = eb + g * 256 + ((lr ^ g) << 3);                    \
      const int ms = mb + g * 256 + ((lk ^ g) << 3);                    \
      _Pragma("unroll")                                                 \
      for (int j2 = 0; j2 < 4; ++j2) {                                  \
        float4 e0 = *(const float4*)&sf[es + j2 * 64];                  \
        float4 e1 = *(const float4*)&sf[es + j2 * 64 + 4];              \
        float4 v0 = *(const float4*)&sf[ms + j2 * 64];                  \
        float4 v1 = *(const float4*)&sf[ms + j2 * 64 + 4];              \
        float av[8] = {e0.x, e0.y, e0.z, e0.w, e1.x, e1.y, e1.z, e1.w}; \
        float bw[8] = {v0.x, v0.y, v0.z, v0.w, v1.x, v1.y, v1.z, v1.w}; \
        _Pragma("unroll")                                               \
        for (int i = 0; i < 8; ++i)                                     \
          _Pragma("unroll")                                             \
          for (int j = 0; j < 8; ++j)                                   \
            acc[i][j] += fabsf(av[i] - bw[j]);                          \
      }                                                                 \
    }                                                                   \
  } while (0)

  LOADC(0);
  STOREC();       // chunk 0 -> LDS (frees gE/gM)
  LOADC(1);       // chunk 1 in flight during compute 0
  COMPUTEC();     // chunk 0
  STOREC();       // chunk 1 -> LDS (same region; same-wave in-order WAR ok)
  // fused output-copy loads (issued now; consumed after summer)
  float4 cm0 = mem4[bid * 1024 + t];
  float4 cm1 = mem4[bid * 1024 + 256 + t];
  float4 cm2 = mem4[bid * 1024 + 512 + t];
  float4 cm3 = mem4[bid * 1024 + 768 + t];
  float4 cd0 = md4[bid * 512 + t];
  float4 cd1 = md4[bid * 512 + 256 + t];
  COMPUTEC();     // chunk 1

  // ---- dump partials into own region (overwrite own staging; no barrier) --
#pragma unroll
  for (int i = 0; i < 8; ++i)
#pragma unroll
    for (int j = 0; j < 8; ++j) {
      const int p = i * 8 + j;
      sf[w * 4096 + l * 64 + (p ^ l)] = acc[i][j];
    }
  __syncthreads();

  // ---- summer: thread t -> row r = t>>2, cols 16*(t&3).. ----
  {
    const int r = t >> 2, cg = t & 3;
    float dmin = 3.4e38f;
#pragma unroll
    for (int cc = 0; cc < 16; ++cc) {
      const int c = cg * 16 + cc;
      const int ll = (r >> 3) * 8 + (c >> 3);
      const int p = (r & 7) * 8 + (c & 7);
      const int off = ll * 64 + (p ^ ll);
      float s = sf[off] + sf[4096 + off] + sf[8192 + off] + sf[12288 + off];
      dmin = fminf(dmin, s);
    }
    dmin = fminf(dmin, __shfl_xor(dmin, 1));
    dmin = fminf(dmin, __shfl_xor(dmin, 2));
    if (cg == 0)  // distances >= 0, init +inf -> uint-bit atomicMin valid
      atomicMin((unsigned int*)out + (b0 + r), __float_as_uint(dmin));
  }

  // ---- complete fused copy ----
  float4* mo = (float4*)(out + OFF_MEM);
  float4* dd = (float4*)(out + OFF_MD);
  mo[bid * 1024 + t] = cm0;
  mo[bid * 1024 + 256 + t] = cm1;
  mo[bid * 1024 + 512 + t] = cm2;
  mo[bid * 1024 + 768 + t] = cm3;
  dd[bid * 512 + t] = cd0;
  dd[bid * 512 + 256 + t] = cd1;
}

// ---------------------------------------------------------------------------
// K3 (k_scatter): sequential circular-buffer update collapsed to
// ballot/prefix + scatter (count starts at M_LEN so positions wrap from 0).
// ---------------------------------------------------------------------------
__global__ __launch_bounds__(256) void k_scatter(float* __restrict__ out,
                                                 const float* __restrict__ enc,
                                                 const float* __restrict__ x) {
  __shared__ int wcount[4];
  int t = threadIdx.x;
  float l = out[t];  // final loss
  bool cond = isfinite(l) && (l <= BETA);
  unsigned long long m = __ballot(cond);
  int lane = t & 63;
  int wv   = t >> 6;
  int pre_in_wave = __popcll(m & ((1ull << lane) - 1ull));
  if (lane == 0) wcount[wv] = (int)__popcll(m);
  __syncthreads();
  int base = 0;
  for (int w = 0; w < wv; ++w) base += wcount[w];
  if (cond) {
    int pos = base + pre_in_wave;  // (M_LEN + prefix) % M_LEN
    float* mrow = out + OFF_MEM + pos * D_OUT;
    const float* erow = enc + t * D_OUT;
    for (int d = 0; d < D_OUT; ++d) mrow[d] = erow[d];
    float* drow = out + OFF_MD + pos * D_IN;
    const float* xrow = x + t * D_IN;
    for (int d = 0; d < D_IN; ++d) drow[d] = xrow[d];
  }
}

// ---------------------------------------------------------------------------
extern "C" void kernel_launch(void* const* d_in, const int* in_sizes, int n_in,
                              void* d_out, int out_size, void* d_ws, size_t ws_size,
                              hipStream_t stream) {
  const float* x      = (const float*)d_in[0];
  const float* mean   = (const float*)d_in[1];
  const float* stdv   = (const float*)d_in[2];
  const float* W1     = (const float*)d_in[3];
  const float* b1     = (const float*)d_in[4];
  const float* memory = (const float*)d_in[5];
  const float* memdat = (const float*)d_in[6];
  float* out = (float*)d_out;
  float* enc = (float*)d_ws;  // 256*256*4 = 256KB scratch

  k_prep<<<dim3(B_ROWS), dim3(256), 0, stream>>>(x, mean, stdv, W1, b1, enc, out);

  k_dist<<<dim3(M_LEN / 64, B_ROWS / 64), dim3(256), 0, stream>>>(
      enc, memory, (const float4*)memory, (const float4*)memdat, out);

  k_scatter<<<dim3(1), dim3(256), 0, stream>>>(out, enc, x);
}

// Round 13
// 26.338 us; speedup vs baseline: 1.3920x; 1.3920x over previous
//
#include <hip/hip_runtime.h>
#include <hip/hip_bf16.h>
#include <math.h>

// Problem constants (from reference setup_inputs)
#define B_ROWS 256
#define D_IN   128
#define D_OUT  256
#define M_LEN  4096
#define BETA   50.0f

// out layout (f32): loss[256] | mem_out[4096*256] | md_out[4096*128]
#define OFF_MEM  (B_ROWS)
#define OFF_MD   (B_ROWS + M_LEN * D_OUT)

// ---------------------------------------------------------------------------
// K1 (k_prep): enc = tanh(norm(x)@W1+b1) and loss init to +inf.
// 256 blocks x 256 threads (one block per batch row).  [r5-proven]
// ---------------------------------------------------------------------------
__global__ __launch_bounds__(256) void k_prep(
    const float* __restrict__ x, const float* __restrict__ mean,
    const float* __restrict__ stdv, const float* __restrict__ W1,
    const float* __restrict__ b1, float* __restrict__ enc,
    float* __restrict__ out) {
  __shared__ float sx[D_IN];
  const int b = blockIdx.x, j = threadIdx.x;
  if (j < D_IN) {
    float s = stdv[j];
    sx[j] = (s == 0.0f) ? 0.0f : (x[b * D_IN + j] - mean[j]) / s;
  }
  __syncthreads();
  float acc = b1[j];
#pragma unroll 8
  for (int k = 0; k < D_IN; ++k) acc = fmaf(sx[k], W1[k * D_OUT + j], acc);
  enc[b * D_OUT + j] = tanhf(acc);
  if (b == 0) ((unsigned int*)out)[j] = 0x7F800000u;  // +inf loss init
}

// ---------------------------------------------------------------------------
// K2 (k_dist): loss[b] = min_m sum_d |enc[b,d] - memory[m,d]|
// [r11 champion body; ONE change: s_setprio(1) around the compute phases.
//  Waves drift freely (no main-loop barriers), so at any instant some waves
//  stage/wait while others run the 2048-instr VALU block -> role diversity;
//  setprio lets compute-phase waves win issue arbitration (T5 regime).]
// 512 blocks (64 m-tiles x 8 b-tiles) x 256 threads. Tile 32b x 64m.
// k-split 4: wave w owns k in [64w,64w+64), 2 chunks of 32 kk, PRIVATE LDS
// region per wave -> NO barriers in the main loop. 4x8 microtile/lane.
// compute() uses a 4-deep rotating register prefetch (compile-time indices)
// so each kk's 3 ds_read_b128 are issued ~512 VALU-cycles ahead of use.
// LDS k-major, XOR swizzle row^=4*(k>>2): staging b32 stores and b128 reads
// <=2-way (free). Staging loads 8-lane-contiguous (128B runs).
// Fused FULL memory->out / mem_data->out copy (loads early, stores late).
// ---------------------------------------------------------------------------
#define TB 32
#define TM 64

__global__ __launch_bounds__(256) void k_dist(
    const float* __restrict__ enc, const float* __restrict__ mem,
    const float4* __restrict__ mem4, const float4* __restrict__ md4,
    float* __restrict__ out) {
  __shared__ __align__(16) float sE[4][32][TB];  // [wave][kk][row^swz] 16KB
  __shared__ __align__(16) float sM[4][32][TM];  // [wave][kk][row^swz] 32KB

  const int t  = threadIdx.x;
  const int w  = t >> 6;     // wave id -> k-quarter
  const int l  = t & 63;
  const int ro = l >> 3;     // 0..7 staging row-offset; compute tr
  const int q  = l & 7;      // 0..7 staging f4-k index; compute tc
  const int m0 = blockIdx.x * TM;
  const int b0 = blockIdx.y * TB;
  const int bid = blockIdx.y * 64 + blockIdx.x;  // gridDim.x == 64

  const float* encp = enc + (b0 + ro) * D_OUT + w * 64 + q * 4;
  const float* memp = mem + (m0 + ro) * D_OUT + w * 64 + q * 4;

  float4 rE[4], rM[8], rE2[4], rM2[8];
  float acc[4][8] = {};

  auto store_lds = [&](const float4* e, const float4* m) {
#pragma unroll
    for (int i = 0; i < 4; ++i) {
      const int row = (i * 8 + ro) ^ (q * 4);
      sE[w][q * 4 + 0][row] = e[i].x;
      sE[w][q * 4 + 1][row] = e[i].y;
      sE[w][q * 4 + 2][row] = e[i].z;
      sE[w][q * 4 + 3][row] = e[i].w;
    }
#pragma unroll
    for (int i = 0; i < 8; ++i) {
      const int row = (i * 8 + ro) ^ (q * 4);
      sM[w][q * 4 + 0][row] = m[i].x;
      sM[w][q * 4 + 1][row] = m[i].y;
      sM[w][q * 4 + 2][row] = m[i].z;
      sM[w][q * 4 + 3][row] = m[i].w;
    }
  };

  auto rdE = [&](int kk) -> float4 {
    const int sw = (kk >> 2) * 4;
    return *(const float4*)&sE[w][kk][(ro * 4) ^ sw];
  };
  auto rdM1 = [&](int kk) -> float4 {
    const int sw = (kk >> 2) * 4;
    return *(const float4*)&sM[w][kk][(q * 8) ^ sw];
  };
  auto rdM2 = [&](int kk) -> float4 {
    const int sw = (kk >> 2) * 4;
    return *(const float4*)&sM[w][kk][(q * 8 + 4) ^ sw];
  };

  auto compute = [&]() {
    __builtin_amdgcn_s_setprio(1);   // favor VALU-phase waves (T5 regime)
    float4 bE[4], bM1[4], bM2[4];  // rotating prefetch regs (static indices)
#pragma unroll
    for (int p = 0; p < 4; ++p) {
      bE[p] = rdE(p); bM1[p] = rdM1(p); bM2[p] = rdM2(p);
    }
#pragma unroll
    for (int kk = 0; kk < 32; ++kk) {
      const int s = kk & 3;
      float4 a  = bE[s];
      float4 v1 = bM1[s];
      float4 v2 = bM2[s];
      if (kk + 4 < 32) {  // issue kk+4's reads before kk's 64 VALU ops
        bE[s] = rdE(kk + 4); bM1[s] = rdM1(kk + 4); bM2[s] = rdM2(kk + 4);
      }
      float av[4] = {a.x, a.y, a.z, a.w};
      float bw[8] = {v1.x, v1.y, v1.z, v1.w, v2.x, v2.y, v2.z, v2.w};
#pragma unroll
      for (int i = 0; i < 4; ++i)
#pragma unroll
        for (int j = 0; j < 8; ++j)
          acc[i][j] += fabsf(av[i] - bw[j]);
    }
    __builtin_amdgcn_s_setprio(0);
  };

  // chunk 0 loads (coalesced: 8 consecutive lanes = 128B run)
#pragma unroll
  for (int i = 0; i < 4; ++i) rE[i] = *(const float4*)(encp + i * 8 * D_OUT);
#pragma unroll
  for (int i = 0; i < 8; ++i) rM[i] = *(const float4*)(memp + i * 8 * D_OUT);
  store_lds(rE, rM);

  // prefetch chunk 1 (+32 k)
#pragma unroll
  for (int i = 0; i < 4; ++i) rE2[i] = *(const float4*)(encp + 32 + i * 8 * D_OUT);
#pragma unroll
  for (int i = 0; i < 8; ++i) rM2[i] = *(const float4*)(memp + 32 + i * 8 * D_OUT);

  // fused output-copy loads (complete by the tail stores)
  float4 cm0 = mem4[bid * 512 + t];
  float4 cm1 = mem4[bid * 512 + 256 + t];
  float4 cd0 = md4[bid * 256 + t];

  compute();               // chunk 0
  store_lds(rE2, rM2);     // same-wave WAR on LDS: in-order per wave
  compute();               // chunk 1

  // ---- combine across the 4 k-quarter waves ----
  float* sf = &sM[0][0][0];
#pragma unroll
  for (int i = 0; i < 4; ++i)
#pragma unroll
    for (int j = 0; j < 8; ++j) {
      const int p = i * 8 + j;
      sf[w * 2048 + l * 32 + (p ^ (l & 31))] = acc[i][j];
    }
  __syncthreads();

  // summer: thread t handles b-row r = t>>3, m-cols (t&7)*8..+7
  {
    const int r = t >> 3, cg = t & 7;
    const int lv = (r >> 2) * 8 + cg;
    float dmin = 3.4e38f;
#pragma unroll
    for (int j = 0; j < 8; ++j) {
      const int p = (r & 3) * 8 + j;
      float s = sf[0 * 2048 + lv * 32 + (p ^ (lv & 31))];
      s += sf[1 * 2048 + lv * 32 + (p ^ (lv & 31))];
      s += sf[2 * 2048 + lv * 32 + (p ^ (lv & 31))];
      s += sf[3 * 2048 + lv * 32 + (p ^ (lv & 31))];
      dmin = fminf(dmin, s);
    }
    dmin = fminf(dmin, __shfl_xor(dmin, 1));
    dmin = fminf(dmin, __shfl_xor(dmin, 2));
    dmin = fminf(dmin, __shfl_xor(dmin, 4));
    if (cg == 0)  // distances >= 0, init +inf -> uint-bit atomicMin valid
      atomicMin((unsigned int*)out + (b0 + r), __float_as_uint(dmin));
  }

  // ---- complete fused copy ----
  float4* mo = (float4*)(out + OFF_MEM);
  float4* dd = (float4*)(out + OFF_MD);
  mo[bid * 512 + t] = cm0;
  mo[bid * 512 + 256 + t] = cm1;
  dd[bid * 256 + t] = cd0;
}

// ---------------------------------------------------------------------------
// K3 (k_scatter): sequential circular-buffer update collapsed to
// ballot/prefix + scatter (count starts at M_LEN so positions wrap from 0).
// ---------------------------------------------------------------------------
__global__ __launch_bounds__(256) void k_scatter(float* __restrict__ out,
                                                 const float* __restrict__ enc,
                                                 const float* __restrict__ x) {
  __shared__ int wcount[4];
  int t = threadIdx.x;
  float l = out[t];  // final loss
  bool cond = isfinite(l) && (l <= BETA);
  unsigned long long m = __ballot(cond);
  int lane = t & 63;
  int wv   = t >> 6;
  int pre_in_wave = __popcll(m & ((1ull << lane) - 1ull));
  if (lane == 0) wcount[wv] = (int)__popcll(m);
  __syncthreads();
  int base = 0;
  for (int w = 0; w < wv; ++w) base += wcount[w];
  if (cond) {
    int pos = base + pre_in_wave;  // (M_LEN + prefix) % M_LEN
    float* mrow = out + OFF_MEM + pos * D_OUT;
    const float* erow = enc + t * D_OUT;
    for (int d = 0; d < D_OUT; ++d) mrow[d] = erow[d];
    float* drow = out + OFF_MD + pos * D_IN;
    const float* xrow = x + t * D_IN;
    for (int d = 0; d < D_IN; ++d) drow[d] = xrow[d];
  }
}

// ---------------------------------------------------------------------------
extern "C" void kernel_launch(void* const* d_in, const int* in_sizes, int n_in,
                              void* d_out, int out_size, void* d_ws, size_t ws_size,
                              hipStream_t stream) {
  const float* x      = (const float*)d_in[0];
  const float* mean   = (const float*)d_in[1];
  const float* stdv   = (const float*)d_in[2];
  const float* W1     = (const float*)d_in[3];
  const float* b1     = (const float*)d_in[4];
  const float* memory = (const float*)d_in[5];
  const float* memdat = (const float*)d_in[6];
  float* out = (float*)d_out;
  float* enc = (float*)d_ws;  // 256*256*4 = 256KB scratch

  k_prep<<<dim3(B_ROWS), dim3(256), 0, stream>>>(x, mean, stdv, W1, b1, enc, out);

  k_dist<<<dim3(M_LEN / TM, B_ROWS / TB), dim3(256), 0, stream>>>(
      enc, memory, (const float4*)memory, (const float4*)memdat, out);

  k_scatter<<<dim3(1), dim3(256), 0, stream>>>(out, enc, x);
}

// Round 14
// 26.326 us; speedup vs baseline: 1.3926x; 1.0004x over previous
//
#include <hip/hip_runtime.h>
#include <hip/hip_bf16.h>
#include <math.h>

// Problem constants (from reference setup_inputs)
#define B_ROWS 256
#define D_IN   128
#define D_OUT  256
#define M_LEN  4096
#define BETA   50.0f

// out layout (f32): loss[256] | mem_out[4096*256] | md_out[4096*128]
#define OFF_MEM  (B_ROWS)
#define OFF_MD   (B_ROWS + M_LEN * D_OUT)

// ---------------------------------------------------------------------------
// K1 (k_prep): enc = tanh(norm(x)@W1+b1) and loss init to +inf.
// 256 blocks x 256 threads (one block per batch row).  [r5-proven]
// ---------------------------------------------------------------------------
__global__ __launch_bounds__(256) void k_prep(
    const float* __restrict__ x, const float* __restrict__ mean,
    const float* __restrict__ stdv, const float* __restrict__ W1,
    const float* __restrict__ b1, float* __restrict__ enc,
    float* __restrict__ out) {
  __shared__ float sx[D_IN];
  const int b = blockIdx.x, j = threadIdx.x;
  if (j < D_IN) {
    float s = stdv[j];
    sx[j] = (s == 0.0f) ? 0.0f : (x[b * D_IN + j] - mean[j]) / s;
  }
  __syncthreads();
  float acc = b1[j];
#pragma unroll 8
  for (int k = 0; k < D_IN; ++k) acc = fmaf(sx[k], W1[k * D_OUT + j], acc);
  enc[b * D_OUT + j] = tanhf(acc);
  if (b == 0) ((unsigned int*)out)[j] = 0x7F800000u;  // +inf loss init
}

// ---------------------------------------------------------------------------
// K2 (k_dist): loss[b] = min_m sum_d |enc[b,d] - memory[m,d]|
// [r13 champion body; ONE change: the accumulate is inline asm
//  "v_add_f32 %0, %0, |%1|" -- forces the VOP3 abs source modifier so each
//  pair costs exactly 2 VALU (v_sub + v_add-abs). r7's profile implied ~2x
//  ideal VALU issue; if the compiler wasn't folding fabsf, this removes a
//  separate v_and per pair (~25% of inner-loop instructions).]
// 512 blocks (64 m-tiles x 8 b-tiles) x 256 threads. Tile 32b x 64m.
// k-split 4: wave w owns k in [64w,64w+64), 2 chunks of 32 kk, PRIVATE LDS
// region per wave -> NO barriers in the main loop. 4x8 microtile/lane.
// compute() uses a 4-deep rotating register prefetch (compile-time indices).
// LDS k-major, XOR swizzle row^=4*(k>>2): staging b32 stores and b128 reads
// <=2-way (free). Staging loads 8-lane-contiguous (128B runs).
// Fused FULL memory->out / mem_data->out copy (loads early, stores late).
// ---------------------------------------------------------------------------
#define TB 32
#define TM 64

__global__ __launch_bounds__(256) void k_dist(
    const float* __restrict__ enc, const float* __restrict__ mem,
    const float4* __restrict__ mem4, const float4* __restrict__ md4,
    float* __restrict__ out) {
  __shared__ __align__(16) float sE[4][32][TB];  // [wave][kk][row^swz] 16KB
  __shared__ __align__(16) float sM[4][32][TM];  // [wave][kk][row^swz] 32KB

  const int t  = threadIdx.x;
  const int w  = t >> 6;     // wave id -> k-quarter
  const int l  = t & 63;
  const int ro = l >> 3;     // 0..7 staging row-offset; compute tr
  const int q  = l & 7;      // 0..7 staging f4-k index; compute tc
  const int m0 = blockIdx.x * TM;
  const int b0 = blockIdx.y * TB;
  const int bid = blockIdx.y * 64 + blockIdx.x;  // gridDim.x == 64

  const float* encp = enc + (b0 + ro) * D_OUT + w * 64 + q * 4;
  const float* memp = mem + (m0 + ro) * D_OUT + w * 64 + q * 4;

  float4 rE[4], rM[8], rE2[4], rM2[8];
  float acc[4][8] = {};

  auto store_lds = [&](const float4* e, const float4* m) {
#pragma unroll
    for (int i = 0; i < 4; ++i) {
      const int row = (i * 8 + ro) ^ (q * 4);
      sE[w][q * 4 + 0][row] = e[i].x;
      sE[w][q * 4 + 1][row] = e[i].y;
      sE[w][q * 4 + 2][row] = e[i].z;
      sE[w][q * 4 + 3][row] = e[i].w;
    }
#pragma unroll
    for (int i = 0; i < 8; ++i) {
      const int row = (i * 8 + ro) ^ (q * 4);
      sM[w][q * 4 + 0][row] = m[i].x;
      sM[w][q * 4 + 1][row] = m[i].y;
      sM[w][q * 4 + 2][row] = m[i].z;
      sM[w][q * 4 + 3][row] = m[i].w;
    }
  };

  auto rdE = [&](int kk) -> float4 {
    const int sw = (kk >> 2) * 4;
    return *(const float4*)&sE[w][kk][(ro * 4) ^ sw];
  };
  auto rdM1 = [&](int kk) -> float4 {
    const int sw = (kk >> 2) * 4;
    return *(const float4*)&sM[w][kk][(q * 8) ^ sw];
  };
  auto rdM2 = [&](int kk) -> float4 {
    const int sw = (kk >> 2) * 4;
    return *(const float4*)&sM[w][kk][(q * 8 + 4) ^ sw];
  };

  auto compute = [&]() {
    __builtin_amdgcn_s_setprio(1);   // favor VALU-phase waves
    float4 bE[4], bM1[4], bM2[4];  // rotating prefetch regs (static indices)
#pragma unroll
    for (int p = 0; p < 4; ++p) {
      bE[p] = rdE(p); bM1[p] = rdM1(p); bM2[p] = rdM2(p);
    }
#pragma unroll
    for (int kk = 0; kk < 32; ++kk) {
      const int s = kk & 3;
      float4 a  = bE[s];
      float4 v1 = bM1[s];
      float4 v2 = bM2[s];
      if (kk + 4 < 32) {  // issue kk+4's reads before kk's 64 VALU ops
        bE[s] = rdE(kk + 4); bM1[s] = rdM1(kk + 4); bM2[s] = rdM2(kk + 4);
      }
      float av[4] = {a.x, a.y, a.z, a.w};
      float bw[8] = {v1.x, v1.y, v1.z, v1.w, v2.x, v2.y, v2.z, v2.w};
#pragma unroll
      for (int i = 0; i < 4; ++i)
#pragma unroll
        for (int j = 0; j < 8; ++j) {
          float d = av[i] - bw[j];
          // forced VOP3 abs-modifier add: exactly 2 VALU per pair
          asm("v_add_f32 %0, %0, |%1|" : "+v"(acc[i][j]) : "v"(d));
        }
    }
    __builtin_amdgcn_s_setprio(0);
  };

  // chunk 0 loads (coalesced: 8 consecutive lanes = 128B run)
#pragma unroll
  for (int i = 0; i < 4; ++i) rE[i] = *(const float4*)(encp + i * 8 * D_OUT);
#pragma unroll
  for (int i = 0; i < 8; ++i) rM[i] = *(const float4*)(memp + i * 8 * D_OUT);
  store_lds(rE, rM);

  // prefetch chunk 1 (+32 k)
#pragma unroll
  for (int i = 0; i < 4; ++i) rE2[i] = *(const float4*)(encp + 32 + i * 8 * D_OUT);
#pragma unroll
  for (int i = 0; i < 8; ++i) rM2[i] = *(const float4*)(memp + 32 + i * 8 * D_OUT);

  // fused output-copy loads (complete by the tail stores)
  float4 cm0 = mem4[bid * 512 + t];
  float4 cm1 = mem4[bid * 512 + 256 + t];
  float4 cd0 = md4[bid * 256 + t];

  compute();               // chunk 0
  store_lds(rE2, rM2);     // same-wave WAR on LDS: in-order per wave
  compute();               // chunk 1

  // ---- combine across the 4 k-quarter waves ----
  float* sf = &sM[0][0][0];
#pragma unroll
  for (int i = 0; i < 4; ++i)
#pragma unroll
    for (int j = 0; j < 8; ++j) {
      const int p = i * 8 + j;
      sf[w * 2048 + l * 32 + (p ^ (l & 31))] = acc[i][j];
    }
  __syncthreads();

  // summer: thread t handles b-row r = t>>3, m-cols (t&7)*8..+7
  {
    const int r = t >> 3, cg = t & 7;
    const int lv = (r >> 2) * 8 + cg;
    float dmin = 3.4e38f;
#pragma unroll
    for (int j = 0; j < 8; ++j) {
      const int p = (r & 3) * 8 + j;
      float s = sf[0 * 2048 + lv * 32 + (p ^ (lv & 31))];
      s += sf[1 * 2048 + lv * 32 + (p ^ (lv & 31))];
      s += sf[2 * 2048 + lv * 32 + (p ^ (lv & 31))];
      s += sf[3 * 2048 + lv * 32 + (p ^ (lv & 31))];
      dmin = fminf(dmin, s);
    }
    dmin = fminf(dmin, __shfl_xor(dmin, 1));
    dmin = fminf(dmin, __shfl_xor(dmin, 2));
    dmin = fminf(dmin, __shfl_xor(dmin, 4));
    if (cg == 0)  // distances >= 0, init +inf -> uint-bit atomicMin valid
      atomicMin((unsigned int*)out + (b0 + r), __float_as_uint(dmin));
  }

  // ---- complete fused copy ----
  float4* mo = (float4*)(out + OFF_MEM);
  float4* dd = (float4*)(out + OFF_MD);
  mo[bid * 512 + t] = cm0;
  mo[bid * 512 + 256 + t] = cm1;
  dd[bid * 256 + t] = cd0;
}

// ---------------------------------------------------------------------------
// K3 (k_scatter): sequential circular-buffer update collapsed to
// ballot/prefix + scatter (count starts at M_LEN so positions wrap from 0).
// ---------------------------------------------------------------------------
__global__ __launch_bounds__(256) void k_scatter(float* __restrict__ out,
                                                 const float* __restrict__ enc,
                                                 const float* __restrict__ x) {
  __shared__ int wcount[4];
  int t = threadIdx.x;
  float l = out[t];  // final loss
  bool cond = isfinite(l) && (l <= BETA);
  unsigned long long m = __ballot(cond);
  int lane = t & 63;
  int wv   = t >> 6;
  int pre_in_wave = __popcll(m & ((1ull << lane) - 1ull));
  if (lane == 0) wcount[wv] = (int)__popcll(m);
  __syncthreads();
  int base = 0;
  for (int w = 0; w < wv; ++w) base += wcount[w];
  if (cond) {
    int pos = base + pre_in_wave;  // (M_LEN + prefix) % M_LEN
    float* mrow = out + OFF_MEM + pos * D_OUT;
    const float* erow = enc + t * D_OUT;
    for (int d = 0; d < D_OUT; ++d) mrow[d] = erow[d];
    float* drow = out + OFF_MD + pos * D_IN;
    const float* xrow = x + t * D_IN;
    for (int d = 0; d < D_IN; ++d) drow[d] = xrow[d];
  }
}

// ---------------------------------------------------------------------------
extern "C" void kernel_launch(void* const* d_in, const int* in_sizes, int n_in,
                              void* d_out, int out_size, void* d_ws, size_t ws_size,
                              hipStream_t stream) {
  const float* x      = (const float*)d_in[0];
  const float* mean   = (const float*)d_in[1];
  const float* stdv   = (const float*)d_in[2];
  const float* W1     = (const float*)d_in[3];
  const float* b1     = (const float*)d_in[4];
  const float* memory = (const float*)d_in[5];
  const float* memdat = (const float*)d_in[6];
  float* out = (float*)d_out;
  float* enc = (float*)d_ws;  // 256*256*4 = 256KB scratch

  k_prep<<<dim3(B_ROWS), dim3(256), 0, stream>>>(x, mean, stdv, W1, b1, enc, out);

  k_dist<<<dim3(M_LEN / TM, B_ROWS / TB), dim3(256), 0, stream>>>(
      enc, memory, (const float4*)memory, (const float4*)memdat, out);

  k_scatter<<<dim3(1), dim3(256), 0, stream>>>(out, enc, x);
}